// Round 17
// baseline (243.268 us; speedup 1.0000x reference)
//
#include <hip/hip_runtime.h>

typedef float f32x4  __attribute__((ext_vector_type(4)));
typedef float f32x16 __attribute__((ext_vector_type(16)));
typedef int   i32x4  __attribute__((ext_vector_type(4)));
typedef int   i32x8  __attribute__((ext_vector_type(8)));

#define AS1 __attribute__((address_space(1)))
#define AS3 __attribute__((address_space(3)))

// ---------------------------------------------------------------------------
// Kernel 1 (R1, proven): per-token quant of x -> fp8 e4m3 + scale
// ---------------------------------------------------------------------------
__global__ __launch_bounds__(256) void quant_x_fp8_kernel(
    const float* __restrict__ x, unsigned char* __restrict__ x8,
    float* __restrict__ xs, int K) {
  int m = blockIdx.x;
  int t = threadIdx.x;
  const f32x4* src = (const f32x4*)(x + (size_t)m * K + t * 16);
  f32x4 v[4];
  float am = 0.0f;
#pragma unroll
  for (int i = 0; i < 4; ++i) {
    v[i] = src[i];
#pragma unroll
    for (int j = 0; j < 4; ++j) am = fmaxf(am, __builtin_fabsf(v[i][j]));
  }
#pragma unroll
  for (int off = 32; off >= 1; off >>= 1)
    am = fmaxf(am, __shfl_xor(am, off, 64));
  __shared__ float red[4];
  int wv = t >> 6, lane = t & 63;
  if (lane == 0) red[wv] = am;
  __syncthreads();
  am = fmaxf(fmaxf(red[0], red[1]), fmaxf(red[2], red[3]));
  am = fmaxf(am, 1e-12f);
  float sc = am / 448.0f;
  if (t == 0) xs[m] = sc;
  i32x4 out;
#pragma unroll
  for (int i = 0; i < 4; ++i) {
    float q0 = v[i][0] / sc, q1 = v[i][1] / sc;
    float q2 = v[i][2] / sc, q3 = v[i][3] / sc;
    int p = __builtin_amdgcn_cvt_pk_fp8_f32(q0, q1, 0, false);
    p = __builtin_amdgcn_cvt_pk_fp8_f32(q2, q3, p, true);
    out[i] = p;
  }
  *(i32x4*)(x8 + (size_t)m * K + t * 16) = out;
}

// ---------------------------------------------------------------------------
// Kernel 2 (R1, proven): weight f32 (fp8-representable) -> fp8 bytes
// ---------------------------------------------------------------------------
__global__ __launch_bounds__(256) void quant_w_fp8_kernel(
    const float* __restrict__ w, unsigned char* __restrict__ w8) {
  size_t idx = (size_t)blockIdx.x * 256 + threadIdx.x;
  const f32x4* src = (const f32x4*)w + idx * 4;
  i32x4 out;
#pragma unroll
  for (int i = 0; i < 4; ++i) {
    f32x4 v = src[i];
    int p = __builtin_amdgcn_cvt_pk_fp8_f32(v[0], v[1], 0, false);
    p = __builtin_amdgcn_cvt_pk_fp8_f32(v[2], v[3], p, true);
    out[i] = p;
  }
  ((i32x4*)w8)[idx] = out;
}

// ---------------------------------------------------------------------------
// Kernel 3: MX-fp8 GEMM. R29 = register-prefetch pipeline at 64x64 wave.
// R28 audit: slot (2 co-res block-bodies) = 2960cy with MFMA 37% / LDS-port
// ~56% / VALU 27% -- NOTHING saturated => latency/sync-bound. Each body
// starts with an lgkm stall (first MFMA waits on fresh ds_reads). Fix:
// read NEXT body's fragments into a second REGISTER set during this body's
// MFMAs (MFMA never lgkm-waits). Why 64x64 wave: at 128x64 the unified
// budget is pinned (acc 128 AGPR + 124 VGPR = 252/256 at 2 waves/SIMD);
// at 64x64 acc = 64 AGPR, K-64 frag set = 32 VGPR -> two sets fit
// (~170 VGPR + 64 AGPR = 234 <= 256).
// Geometry: 128x128 block (R23-validated frame+epilogue), 256 thr, 4 waves
// 2(wr)x2(wc), wave 64x64, acc[2][2] f32x16 (AGPR; even-body ratio-fold,
// R20-validated). K-64 bodies (64 total), K-64 LDS layout/swizzle/anchors/
// staging = R25/R27-validated. LDS = 3 bufs x {A 8KB @0, B 8KB @8192} =
// 49152 -- the exact size R27 PROVED co-resides 2 blocks/CU.
// Body T: RD_F frags(T+1) -> alternate set [from buf (T+1)%3, staged at
// T-2, published barrier(T-1)]; STG body T+3 -> buf T%3 [WAR: last read
// body T-1, retired by lgkm(0) before barrier(T-1)]; 4 MFMA from current
// set (zero lgkm stall); lgkm(0); vmcnt(4); barrier.
// vmcnt ledger (4 gloads/body): end-of-T queue = [(T+2):4 from T-1,
// (T+3):4 from T]; vmcnt(4) retires (T+2) (read in body T+1), leaves
// (T+3) in flight ACROSS the barrier. Cover ~1.5 bodies.
// Prologue: stage bodies 0,1,2 (12 gloads); vmcnt(4) retires 0,1; barrier;
// RD_F frags(0)->setE; lgkm(0); barrier (block-wide retire before body 0
// stages body 3 into buf0). Tail: bodies 61/62 no stage, vmcnt(0);
// body 63 compute-only.
// Tripwires: LDS_Block 49152; WRITE == 131072KB (else spill); VGPR
// 110-140; Occupancy ~20-25 (2 blocks/CU).
// ---------------------------------------------------------------------------
__global__ __launch_bounds__(256, 2) void gemm_mxfp8_kernel(
    const unsigned char* __restrict__ A8,   // [M][K] fp8
    const unsigned char* __restrict__ W8,   // [N][K] fp8
    const float* __restrict__ xs,           // [M]
    const float* __restrict__ wsinv,        // [N/128][K/128]
    float* __restrict__ Y,                  // [M][N] f32
    int M, int N, int K) {
  const int KB = K >> 7;  // K/128 scale tiles (32); bodies = 64

  int bid = blockIdx.x, nwg = gridDim.x;
  int wg = (bid & 7) * (nwg >> 3) + (bid >> 3);
  int mt = M >> 7;                  // 32
  int bm = wg & (mt - 1);
  int bn = wg / mt;                 // 0..63
  int m0 = bm << 7, n0 = bn << 7;   // 128 x 128 tile

  __shared__ __align__(16) char lds[49152];  // bufs @0, @16384, @32768

  const int tid = threadIdx.x, wv = tid >> 6, lane = tid & 63;
  const int wr = wv >> 1, wc = wv & 1;          // 2 x 2 wave grid
  const int l31 = lane & 31, hi2 = lane >> 5;

  // K-64 anchors (R25/R27-validated): row r at line r>>1; 16B-slot s of
  // row r stored at slot8 = ((r&1)<<2 | s) ^ ((r>>1)&7).
  const int lineB = (l31 >> 1) * 128;
  const int par4 = (l31 & 1) << 2;
  const int xr = (l31 >> 1) & 7;
  const int s0 = 2 * hi2, s1 = 2 * hi2 + 1;
  const int slotL = ((par4 | s0) ^ xr) << 4;
  const int slotH = ((par4 | s1) ^ xr) << 4;
  // A rows: wr*64 + mj*32 + l31 -> byte base wr*4096 + mj*2048
  const int aL0 = wr * 4096 + lineB + slotL;
  const int aH0 = wr * 4096 + lineB + slotH;
  const int aL1 = aL0 + 2048, aH1 = aH0 + 2048;
  // B rows: wc*64 + nj*32 + l31 -> byte base 8192 + wc*4096 + nj*2048
  const int bL0 = 8192 + wc * 4096 + lineB + slotL;
  const int bH0 = 8192 + wc * 4096 + lineB + slotH;
  const int bL1 = bL0 + 2048, bH1 = bH0 + 2048;

  // staging (R25/R27-validated): dest = buf + sweep*4096 + tid*16 (linear);
  // src row = 64*sweep + 2*(tid>>3) + (inv>>2), col = (inv&3)*16.
  const int stgD = tid << 4;
  const int inv = (tid & 7) ^ ((tid >> 3) & 7);
  const int rLoc = 2 * (tid >> 3) + (inv >> 2);
  const int cSrc = (inv & 3) << 4;
  const size_t rowB = (size_t)K;  // fp8: 1 byte/elem
  const size_t g64r = 64 * rowB;  // 64-row sweep stride
  const char* pA = (const char*)A8 + (size_t)(m0 + rLoc) * rowB + cSrc;
  const char* pB = (const char*)W8 + (size_t)(n0 + rLoc) * rowB + cSrc;

  const float* wsv = wsinv + (size_t)bn * KB;  // one scale row per 128 cols

  f32x16 acc[2][2];
#pragma unroll
  for (int i = 0; i < 2; ++i)
#pragma unroll
    for (int j = 0; j < 2; ++j) acc[i][j] = (f32x16)0.0f;

  // two register fragment sets (E/O), statically addressed
  i32x8 afE[2], bfE[2], afO[2], bfO[2];

#define GL(SRC, DST)                                                           \
  __builtin_amdgcn_global_load_lds((const AS1 void*)(SRC), (AS3 void*)(DST),   \
                                   16, 0, 0)
// 128-row x 64B panel (8KB): 2 sweeps
#define STG_P(COND, SB, SRC)                                                   \
  if (COND) {                                                                  \
    const char* s_ = (SRC);                                                    \
    char* d_ = lds + (SB) + stgD;                                              \
    GL(s_, d_);                                                                \
    GL(s_ + g64r, d_ + 4096);                                                  \
  }
// stage one body (A panel -> BUF+0, B panel -> BUF+8192): 4 gloads
#define STG(COND, BUF)                                                         \
  STG_P(COND, (BUF), pAs)                                                      \
  STG_P(COND, (BUF) + 8192, pBs)

// full frag set for one body from buf base BUF: 8 ds_read_b128
#define RD_F(BUF, AF, BF)                                                      \
  {                                                                            \
    const char* q_ = lds + (BUF);                                              \
    i32x4 t0_ = *(const i32x4*)(q_ + aL0);                                     \
    i32x4 t1_ = *(const i32x4*)(q_ + aH0);                                     \
    AF[0] = __builtin_shufflevector(t0_, t1_, 0, 1, 2, 3, 4, 5, 6, 7);         \
    t0_ = *(const i32x4*)(q_ + aL1);                                           \
    t1_ = *(const i32x4*)(q_ + aH1);                                           \
    AF[1] = __builtin_shufflevector(t0_, t1_, 0, 1, 2, 3, 4, 5, 6, 7);         \
    t0_ = *(const i32x4*)(q_ + bL0);                                           \
    t1_ = *(const i32x4*)(q_ + bH0);                                           \
    BF[0] = __builtin_shufflevector(t0_, t1_, 0, 1, 2, 3, 4, 5, 6, 7);         \
    t0_ = *(const i32x4*)(q_ + bL1);                                           \
    t1_ = *(const i32x4*)(q_ + bH1);                                           \
    BF[1] = __builtin_shufflevector(t0_, t1_, 0, 1, 2, 3, 4, 5, 6, 7);         \
  }

// 4 MFMA with ratio-fold (even bodies): acc = mfma(af, bf, acc*r)
#define MME(AF, BF, R_)                                                        \
  _Pragma("unroll") for (int mj = 0; mj < 2; ++mj)                             \
  _Pragma("unroll") for (int nj = 0; nj < 2; ++nj) {                           \
    _Pragma("unroll") for (int q = 0; q < 16; ++q)                             \
        acc[mj][nj][q] *= (R_);                                                \
    acc[mj][nj] = __builtin_amdgcn_mfma_scale_f32_32x32x64_f8f6f4(             \
        AF[mj], BF[nj], acc[mj][nj], 0, 0, 0, 0x7f7f7f7f, 0, 0x7f7f7f7f);      \
  }
// 4 MFMA direct-chain (odd bodies)
#define MMD(AF, BF)                                                            \
  _Pragma("unroll") for (int mj = 0; mj < 2; ++mj)                             \
  _Pragma("unroll") for (int nj = 0; nj < 2; ++nj)                             \
    acc[mj][nj] = __builtin_amdgcn_mfma_scale_f32_32x32x64_f8f6f4(             \
        AF[mj], BF[nj], acc[mj][nj], 0, 0, 0, 0x7f7f7f7f, 0, 0x7f7f7f7f);

// body (even): compute set E with fold, load set O from RDB, stage -> STB
#define BODY_E(SC_, RDB, STB, G, VM)                                           \
  {                                                                            \
    float sc_ = (SC_);                                                         \
    float r_ = sp_ / sc_;                                                      \
    sp_ = sc_;                                                                 \
    RD_F(RDB, afO, bfO);                                                       \
    STG(G, STB);                                                               \
    __builtin_amdgcn_s_setprio(1);                                             \
    MME(afE, bfE, r_);                                                         \
    __builtin_amdgcn_s_setprio(0);                                             \
    asm volatile("s_waitcnt lgkmcnt(0)" ::: "memory");                         \
    asm volatile("s_waitcnt " VM ::: "memory");                                \
    __builtin_amdgcn_s_barrier();                                              \
    pAs += 64;                                                                 \
    pBs += 64;                                                                 \
  }
// body (odd): compute set O direct, load set E
#define BODY_O(RDB, STB, G, VM)                                                \
  {                                                                            \
    RD_F(RDB, afE, bfE);                                                       \
    STG(G, STB);                                                               \
    __builtin_amdgcn_s_setprio(1);                                             \
    MMD(afO, bfO);                                                             \
    __builtin_amdgcn_s_setprio(0);                                             \
    asm volatile("s_waitcnt lgkmcnt(0)" ::: "memory");                         \
    asm volatile("s_waitcnt " VM ::: "memory");                                \
    __builtin_amdgcn_s_barrier();                                              \
    pAs += 64;                                                                 \
    pBs += 64;                                                                 \
  }

  // prologue: stage bodies 0,1,2 -> bufs 0,1,2 (12 gloads); vmcnt(4)
  // retires 0,1 (leaves body2's 4 = steady invariant); publish; read
  // frags(0) -> setE; lgkm(0)+barrier (block-wide retire of buf0 reads
  // before body 0 stages body 3 into buf0).
  {
    const char* pAs = pA;
    const char* pBs = pB;
    STG(true, 0);
    pAs += 64; pBs += 64;
    STG(true, 16384);
    pAs += 64; pBs += 64;
    STG(true, 32768);
  }
  asm volatile("s_waitcnt vmcnt(4)" ::: "memory");
  __builtin_amdgcn_s_barrier();
  RD_F(0, afE, bfE);
  asm volatile("s_waitcnt lgkmcnt(0)" ::: "memory");
  __builtin_amdgcn_s_barrier();

  const char* pAs = pA + 192;  // body 0 stages body 3
  const char* pBs = pB + 192;
  float sp_ = wsv[0];          // previous-tile scale (ratio = 1 at t = 0)

  // bodies 0..59 in 6-body groups (buf period 3 x set period 2):
  // body b: reads frags(b+1) from buf (b+1)%3; stages b+3 -> buf b%3.
#pragma unroll 1
  for (int t0 = 0; t0 < 30; t0 += 3) {
    BODY_E(wsv[t0],     16384, 0,     true, "vmcnt(4)")  // b%6=0: rd1 st0
    BODY_O(             32768, 16384, true, "vmcnt(4)")  // b%6=1: rd2 st1
    BODY_E(wsv[t0 + 1], 0,     32768, true, "vmcnt(4)")  // b%6=2: rd0 st2
    BODY_O(             16384, 0,     true, "vmcnt(4)")  // b%6=3: rd1 st0
    BODY_E(wsv[t0 + 2], 32768, 16384, true, "vmcnt(4)")  // b%6=4: rd2 st1
    BODY_O(             0,     32768, true, "vmcnt(4)")  // b%6=5: rd0 st2
  }
  // tail: bodies 60..63 (scale tiles 30, 31)
  BODY_E(wsv[30], 16384, 0,     true,  "vmcnt(4)")  // b=60: stages body 63
  BODY_O(         32768, 0,     false, "vmcnt(0)")  // b=61: no stage
  BODY_E(wsv[31], 0,     0,     false, "vmcnt(0)")  // b=62: reads frags(63)
  // b=63: compute-only (set O), no read/stage
  __builtin_amdgcn_s_setprio(1);
  MMD(afO, bfO);
  __builtin_amdgcn_s_setprio(0);

#undef BODY_O
#undef BODY_E
#undef MMD
#undef MME
#undef RD_F
#undef STG
#undef STG_P
#undef GL

  // epilogue (R23-validated C/D mapping): col=l31, row=q*8+hi2*4+j.
  // acc is in s_last domain: Y = acc * s_last * xs[row].
  const float sl_ = sp_;
#pragma unroll
  for (int mj = 0; mj < 2; ++mj)
#pragma unroll
    for (int nj = 0; nj < 2; ++nj) {
      int col = n0 + wc * 64 + nj * 32 + l31;
#pragma unroll
      for (int q = 0; q < 4; ++q) {
        int row0 = m0 + wr * 64 + mj * 32 + q * 8 + hi2 * 4;
        f32x4 sv = *(const f32x4*)(xs + row0);
#pragma unroll
        for (int j = 0; j < 4; ++j)
          Y[(size_t)(row0 + j) * N + col] = acc[mj][nj][q * 4 + j] * sv[j] * sl_;
      }
    }
}

// ---------------------------------------------------------------------------
extern "C" void kernel_launch(void* const* d_in, const int* in_sizes, int n_in,
                              void* d_out, int out_size, void* d_ws, size_t ws_size,
                              hipStream_t stream) {
  const float* x     = (const float*)d_in[0];   // [B,S,K] f32
  const float* w     = (const float*)d_in[1];   // [N,K] f32 (fp8-representable)
  const float* wsinv = (const float*)d_in[2];   // [N/128,K/128] f32
  float* y = (float*)d_out;

  const int K = 4096;
  const int M = in_sizes[0] / K;   // 4096
  const int N = in_sizes[1] / K;   // 8192

  unsigned char* x8 = (unsigned char*)d_ws;                       // M*K
  float* xs = (float*)((char*)d_ws + (size_t)M * K);              // M floats
  unsigned char* w8 =
      (unsigned char*)d_ws + (size_t)M * K + (size_t)M * 4;       // N*K

  quant_x_fp8_kernel<<<M, 256, 0, stream>>>(x, x8, xs, K);
  quant_w_fp8_kernel<<<(int)(((size_t)N * K / 16 + 255) / 256), 256, 0,
                       stream>>>(w, w8);

  dim3 grid((M / 128) * (N / 128));  // 2048
  gemm_mxfp8_kernel<<<grid, 256, 0, stream>>>(x8, w8, xs, wsinv, y, M, N, K);
}

// Round 19
// 209.580 us; speedup vs baseline: 1.1607x; 1.1607x over previous
//
#include <hip/hip_runtime.h>

typedef float f32x4  __attribute__((ext_vector_type(4)));
typedef float f32x16 __attribute__((ext_vector_type(16)));
typedef int   i32x4  __attribute__((ext_vector_type(4)));
typedef int   i32x8  __attribute__((ext_vector_type(8)));

#define AS1 __attribute__((address_space(1)))
#define AS3 __attribute__((address_space(3)))

// ---------------------------------------------------------------------------
// Kernel 1 (R30): fused quant pre-pass. Blocks [0, M) = per-token quant of
// x (R1-proven body); blocks [M, M+WB) = weight f32->fp8 (R1-proven body).
// Both memory-bound; fusing saves a launch and lets W-blocks fill CUs while
// the X tail drains.
// ---------------------------------------------------------------------------
__global__ __launch_bounds__(256) void quant_fused_kernel(
    const float* __restrict__ x, unsigned char* __restrict__ x8,
    float* __restrict__ xs, const float* __restrict__ w,
    unsigned char* __restrict__ w8, int K, int M) {
  int bid = blockIdx.x;
  int t = threadIdx.x;
  if (bid < M) {
    // ---- quant_x body (R1-proven) ----
    int m = bid;
    const f32x4* src = (const f32x4*)(x + (size_t)m * K + t * 16);
    f32x4 v[4];
    float am = 0.0f;
#pragma unroll
    for (int i = 0; i < 4; ++i) {
      v[i] = src[i];
#pragma unroll
      for (int j = 0; j < 4; ++j) am = fmaxf(am, __builtin_fabsf(v[i][j]));
    }
#pragma unroll
    for (int off = 32; off >= 1; off >>= 1)
      am = fmaxf(am, __shfl_xor(am, off, 64));
    __shared__ float red[4];
    int wv = t >> 6, lane = t & 63;
    if (lane == 0) red[wv] = am;
    __syncthreads();
    am = fmaxf(fmaxf(red[0], red[1]), fmaxf(red[2], red[3]));
    am = fmaxf(am, 1e-12f);
    float sc = am / 448.0f;
    if (t == 0) xs[m] = sc;
    i32x4 out;
#pragma unroll
    for (int i = 0; i < 4; ++i) {
      float q0 = v[i][0] / sc, q1 = v[i][1] / sc;
      float q2 = v[i][2] / sc, q3 = v[i][3] / sc;
      int p = __builtin_amdgcn_cvt_pk_fp8_f32(q0, q1, 0, false);
      p = __builtin_amdgcn_cvt_pk_fp8_f32(q2, q3, p, true);
      out[i] = p;
    }
    *(i32x4*)(x8 + (size_t)m * K + t * 16) = out;
  } else {
    // ---- quant_w body (R1-proven) ----
    size_t idx = (size_t)(bid - M) * 256 + t;
    const f32x4* src = (const f32x4*)w + idx * 4;
    i32x4 out;
#pragma unroll
    for (int i = 0; i < 4; ++i) {
      f32x4 v = src[i];
      int p = __builtin_amdgcn_cvt_pk_fp8_f32(v[0], v[1], 0, false);
      p = __builtin_amdgcn_cvt_pk_fp8_f32(v[2], v[3], p, true);
      out[i] = p;
    }
    ((i32x4*)w8)[idx] = out;
  }
}

// ---------------------------------------------------------------------------
// Kernel 3: MX-fp8 GEMM. R30 = R28 (proven best: 158.2us GEMM) + lgkm-
// optimal read ordering inside the body. (R31 = R30 resubmitted: the R30
// bench died with an infra-level UnresponsiveContainer before producing
// data; the kernel deltas vs validated R28 -- read reordering within the
// proven body, fused quant launch with independent proven bodies -- have
// no plausible mechanism for a container disconnect.)
// R29 post-mortem: 128^2-tile register-prefetch regressed (FETCH 517MB --
// worse reuse; MfmaUtil 31%; lgkm(0) drain not covered by the short MFMA
// phase). Reverted. R28 budget audit: wave 128x64 pins the unified file
// (acc 128 AGPR + 124 VGPR = 252/256 at 2 waves/SIMD) -> no frag-dbuf
// headroom; LDS at the proven co-residency ceiling (65536). R30 harvest:
// reorder body reads {B0,A0}->MFMA(0,0)->B1->MFMA(0,1)->A1->... so each
// MFMA waits only on its own 2-4 ds_reads (R28 waited on all 6 before the
// first MFMA). Everything else byte-identical to R28:
// 256 thr, 4 waves 2(wr)x2(wc), wave 128x64, block 256x128, K-64 bodies;
// LDS = A x3 (16KB @0,16384,32768) + B x2 (8KB @49152,57344) = 65536.
// Body T: read bufA(T%3), bufB(T%2); stage B(T+1)->bufB((T+1)%2), then
// A(T+2)->bufA((T+2)%3); MFMA; vmcnt(4); barrier.
// Ledger: end-of-T queue = [A(T+1):4, B(T+1):2, A(T+2):4]; vmcnt(4)
// retires A(T+1)+B(T+1), leaves A(T+2) in flight ACROSS the barrier
// (never drains in main loop). WAR: stage targets = bufs last read in
// body T-1, >=1 closing barrier before issue (R17 rule). 6-body static
// groups (lcm(3,2)); tail bodies 60..63 with vmcnt(0) at 62/63.
// K-64 layout/swizzle/anchors/staging R25/R27-validated; fold R20-
// validated (even bodies acc*=s_prev/s_cur, C-chain; epilogue * s_last);
// epilogue mapping R24/R25/R27-proven.
// Tripwires: LDS_Block 65536; WRITE == 131072KB (else spill); VGPR
// ~124; Occupancy ~20 (2 blocks/CU).
// ---------------------------------------------------------------------------
__global__ __launch_bounds__(256, 2) void gemm_mxfp8_kernel(
    const unsigned char* __restrict__ A8,   // [M][K] fp8
    const unsigned char* __restrict__ W8,   // [N][K] fp8
    const float* __restrict__ xs,           // [M]
    const float* __restrict__ wsinv,        // [N/128][K/128]
    float* __restrict__ Y,                  // [M][N] f32
    int M, int N, int K) {
  const int KB = K >> 7;  // K/128 scale tiles (32); bodies = 64

  int bid = blockIdx.x, nwg = gridDim.x;
  int wg = (bid & 7) * (nwg >> 3) + (bid >> 3);
  int mt = M >> 8;                  // 16
  int bm = wg & (mt - 1);
  int bn = wg / mt;                 // 0..63
  int m0 = bm << 8, n0 = bn << 7;   // 256 x 128 tile

  // A bufs @0,@16384,@32768 (16KB); B bufs @49152,@57344 (8KB) = 65536
  __shared__ __align__(16) char lds[65536];

  const int tid = threadIdx.x, wv = tid >> 6, lane = tid & 63;
  const int wr = wv >> 1, wc = wv & 1;          // 2 x 2 wave grid
  const int l31 = lane & 31, hi2 = lane >> 5;

  // read anchors for the K-64 interleaved layout (R25/R27-validated):
  // anchor(s) = (l31>>1)*128 + ((((l31&1)<<2)|s) ^ ((l31>>1)&7))*16
  const int lineB = (l31 >> 1) * 128;
  const int par4 = (l31 & 1) << 2;
  const int xr = (l31 >> 1) & 7;
  const int s0 = 2 * hi2, s1 = 2 * hi2 + 1;
  const int aL = wr * 8192 + lineB + ((par4 | s0) ^ xr) * 16;
  const int aH = wr * 8192 + lineB + ((par4 | s1) ^ xr) * 16;
  const int bL = wc * 4096 + lineB + ((par4 | s0) ^ xr) * 16;
  const int bH = wc * 4096 + lineB + ((par4 | s1) ^ xr) * 16;

  // staging (R25/R27-validated): dest = buf + sweep*4096 + tid*16 (linear);
  // src row = 64*sweep + 2*(tid>>3) + (inv>>2), col = (inv&3)*16.
  const int stgD = tid << 4;
  const int inv = (tid & 7) ^ ((tid >> 3) & 7);
  const int rLoc = 2 * (tid >> 3) + (inv >> 2);
  const int cSrc = (inv & 3) << 4;
  const size_t rowB = (size_t)K;  // fp8: 1 byte/elem
  const size_t g64r = 64 * rowB;  // 64-row sweep stride
  const char* pA = (const char*)A8 + (size_t)(m0 + rLoc) * rowB + cSrc;
  const char* pB = (const char*)W8 + (size_t)(n0 + rLoc) * rowB + cSrc;

  const float* wsv = wsinv + (size_t)bn * KB;  // N-tile 128 = one scale row

  f32x16 acc[4][2];
#pragma unroll
  for (int i = 0; i < 4; ++i)
#pragma unroll
    for (int j = 0; j < 2; ++j) acc[i][j] = (f32x16)0.0f;

  i32x8 af, bf[2];

#define GL(SRC, DST)                                                           \
  __builtin_amdgcn_global_load_lds((const AS1 void*)(SRC), (AS3 void*)(DST),   \
                                   16, 0, 0)
// A panel (256 rows x 64B = 16KB): 4 sweeps
#define STG_A(COND, SB, SRC)                                                   \
  if (COND) {                                                                  \
    const char* s_ = (SRC);                                                    \
    char* d_ = lds + (SB) + stgD;                                              \
    GL(s_, d_);                                                                \
    GL(s_ + g64r, d_ + 4096);                                                  \
    GL(s_ + 2 * g64r, d_ + 8192);                                              \
    GL(s_ + 3 * g64r, d_ + 12288);                                             \
  }
// B panel (128 rows x 64B = 8KB): 2 sweeps (absolute base)
#define STG_B(COND, SB, SRC)                                                   \
  if (COND) {                                                                  \
    const char* s_ = (SRC);                                                    \
    char* d_ = lds + (SB) + stgD;                                              \
    GL(s_, d_);                                                                \
    GL(s_ + g64r, d_ + 4096);                                                  \
  }

// A frag for one mj (K-64), literal buf base RB: 2 ds_read_b128 -> af
#define RD_A(RB, MJ)                                                           \
  {                                                                            \
    const char* p_ = lds + (RB) + (MJ) * 2048;                                 \
    i32x4 lo = *(const i32x4*)(p_ + aL);                                       \
    i32x4 hi = *(const i32x4*)(p_ + aH);                                       \
    af = __builtin_shufflevector(lo, hi, 0, 1, 2, 3, 4, 5, 6, 7);              \
  }
// B frag for one nj (K-64), literal buf base RB (absolute)
#define RD_B(RB, NJ)                                                           \
  {                                                                            \
    const char* p_ = lds + (RB) + (NJ) * 2048;                                 \
    i32x4 lo = *(const i32x4*)(p_ + bL);                                       \
    i32x4 hi = *(const i32x4*)(p_ + bH);                                       \
    bf[NJ] = __builtin_shufflevector(lo, hi, 0, 1, 2, 3, 4, 5, 6, 7);          \
  }

// fold + MFMA (even bodies): acc = mfma(af, bf, acc*r)
#define MMFF(MJ, NJ, R_)                                                       \
  {                                                                            \
    _Pragma("unroll") for (int q = 0; q < 16; ++q)                             \
        acc[MJ][NJ][q] *= (R_);                                                \
    acc[MJ][NJ] = __builtin_amdgcn_mfma_scale_f32_32x32x64_f8f6f4(             \
        af, bf[NJ], acc[MJ][NJ], 0, 0, 0, 0x7f7f7f7f, 0, 0x7f7f7f7f);          \
  }
// direct MFMA (odd bodies; R_ ignored): acc = mfma(af, bf, acc)
#define MMFD(MJ, NJ, R_)                                                       \
  acc[MJ][NJ] = __builtin_amdgcn_mfma_scale_f32_32x32x64_f8f6f4(               \
      af, bf[NJ], acc[MJ][NJ], 0, 0, 0, 0x7f7f7f7f, 0, 0x7f7f7f7f);

// body: lgkm-optimal order -- {B0,A0} -> MFMA(0,0) (4 reads) -> B1 ->
// MFMA(0,1) -> A1 -> MFMA(1,*) -> ... Each MFMA waits only on its own
// operands (R28 waited on all 6 before the first MFMA). Stages issued
// right after the first reads; counted vmcnt; 1 barrier.
#define BODY_CORE(F, R_, AR, BR, BS, AS, GB, GA, VM)                           \
  {                                                                            \
    RD_B(BR, 0);                                                               \
    RD_A(AR, 0);                                                               \
    STG_B(GB, BS, pBs);                                                        \
    STG_A(GA, AS, pAs);                                                        \
    __builtin_amdgcn_s_setprio(1);                                             \
    F(0, 0, R_);                                                               \
    __builtin_amdgcn_s_setprio(0);                                             \
    RD_B(BR, 1);                                                               \
    __builtin_amdgcn_s_setprio(1);                                             \
    F(0, 1, R_);                                                               \
    __builtin_amdgcn_s_setprio(0);                                             \
    RD_A(AR, 1);                                                               \
    __builtin_amdgcn_s_setprio(1);                                             \
    F(1, 0, R_);                                                               \
    F(1, 1, R_);                                                               \
    __builtin_amdgcn_s_setprio(0);                                             \
    RD_A(AR, 2);                                                               \
    __builtin_amdgcn_s_setprio(1);                                             \
    F(2, 0, R_);                                                               \
    F(2, 1, R_);                                                               \
    __builtin_amdgcn_s_setprio(0);                                             \
    RD_A(AR, 3);                                                               \
    __builtin_amdgcn_s_setprio(1);                                             \
    F(3, 0, R_);                                                               \
    F(3, 1, R_);                                                               \
    __builtin_amdgcn_s_setprio(0);                                             \
    asm volatile("s_waitcnt " VM ::: "memory");                                \
    __builtin_amdgcn_s_barrier();                                              \
    pAs += 64;                                                                 \
    pBs += 64;                                                                 \
  }

#define BODY_E(SC_, AR, BR, BS, AS, GB, GA, VM)                                \
  {                                                                            \
    float sc_ = (SC_);                                                         \
    float r_ = sp_ / sc_;                                                      \
    sp_ = sc_;                                                                 \
    BODY_CORE(MMFF, r_, AR, BR, BS, AS, GB, GA, VM)                            \
  }
#define BODY_O(AR, BR, BS, AS, GB, GA, VM)                                     \
  BODY_CORE(MMFD, 0.0f, AR, BR, BS, AS, GB, GA, VM)

  // prologue: A(0)->A0, B(0)->B0, A(1)->A1 (10 gloads); vmcnt(4) retires
  // A0+B0, leaves A(1):4 = steady entry invariant; barrier publishes.
  STG_A(true, 0, pA);
  STG_B(true, 49152, pB);
  STG_A(true, 16384, pA + 64);
  asm volatile("s_waitcnt vmcnt(4)" ::: "memory");
  __builtin_amdgcn_s_barrier();

  const char* pAs = pA + 128;  // A stage source (body T stages A(T+2))
  const char* pBs = pB + 64;   // B stage source (body T stages B(T+1))
  float sp_ = wsv[0];          // previous-tile scale (ratio = 1 at t = 0)

  // 6-body groups (bufA period 3 x bufB period 2), bodies 0..59;
  // body b: reads A(b%3), B(b%2); stages B->B((b+1)%2), A->A((b+2)%3).
#pragma unroll 1
  for (int t0 = 0; t0 < 30; t0 += 3) {
    float sA_ = wsv[t0], sB_ = wsv[t0 + 1], sC_ = wsv[t0 + 2];
    BODY_E(sA_, 0,     49152, 57344, 32768, true, true, "vmcnt(4)")
    BODY_O(     16384, 57344, 49152, 0,     true, true, "vmcnt(4)")
    BODY_E(sB_, 32768, 49152, 57344, 16384, true, true, "vmcnt(4)")
    BODY_O(     0,     57344, 49152, 32768, true, true, "vmcnt(4)")
    BODY_E(sC_, 16384, 49152, 57344, 0,     true, true, "vmcnt(4)")
    BODY_O(     32768, 57344, 49152, 16384, true, true, "vmcnt(4)")
  }
  // tail: bodies 60..63 (scale tiles 30, 31)
  BODY_E(wsv[30], 0,     49152, 57344, 32768, true,  true,  "vmcnt(4)")
  BODY_O(         16384, 57344, 49152, 0,     true,  true,  "vmcnt(4)")
  BODY_E(wsv[31], 32768, 49152, 57344, 0,     true,  false, "vmcnt(0)")
  BODY_O(         0,     57344, 49152, 0,     false, false, "vmcnt(0)")

#undef BODY_O
#undef BODY_E
#undef BODY_CORE
#undef MMFD
#undef MMFF
#undef RD_B
#undef RD_A
#undef STG_B
#undef STG_A
#undef GL

  // epilogue (R24/R25/R27-proven mapping, wave 128x64): col=l31,
  // row=q*8+hi2*4+j. acc is in s_last domain: Y = acc * s_last * xs[row].
  const float sl_ = sp_;
#pragma unroll
  for (int mj = 0; mj < 4; ++mj)
#pragma unroll
    for (int nj = 0; nj < 2; ++nj) {
      int col = n0 + wc * 64 + nj * 32 + l31;
#pragma unroll
      for (int q = 0; q < 4; ++q) {
        int row0 = m0 + wr * 128 + mj * 32 + q * 8 + hi2 * 4;
        f32x4 sv = *(const f32x4*)(xs + row0);
#pragma unroll
        for (int j = 0; j < 4; ++j)
          Y[(size_t)(row0 + j) * N + col] = acc[mj][nj][q * 4 + j] * sv[j] * sl_;
      }
    }
}

// ---------------------------------------------------------------------------
extern "C" void kernel_launch(void* const* d_in, const int* in_sizes, int n_in,
                              void* d_out, int out_size, void* d_ws, size_t ws_size,
                              hipStream_t stream) {
  const float* x     = (const float*)d_in[0];   // [B,S,K] f32
  const float* w     = (const float*)d_in[1];   // [N,K] f32 (fp8-representable)
  const float* wsinv = (const float*)d_in[2];   // [N/128,K/128] f32
  float* y = (float*)d_out;

  const int K = 4096;
  const int M = in_sizes[0] / K;   // 4096
  const int N = in_sizes[1] / K;   // 8192

  unsigned char* x8 = (unsigned char*)d_ws;                       // M*K
  float* xs = (float*)((char*)d_ws + (size_t)M * K);              // M floats
  unsigned char* w8 =
      (unsigned char*)d_ws + (size_t)M * K + (size_t)M * 4;       // N*K

  int wBlocks = (int)(((size_t)N * K / 16 + 255) / 256);          // 8192
  quant_fused_kernel<<<M + wBlocks, 256, 0, stream>>>(x, x8, xs, w, w8, K, M);

  dim3 grid((M / 256) * (N / 128));  // 1024
  gemm_mxfp8_kernel<<<grid, 256, 0, stream>>>(x8, w8, xs, wsinv, y, M, N, K);
}

// Round 20
// 207.885 us; speedup vs baseline: 1.1702x; 1.0082x over previous
//
#include <hip/hip_runtime.h>

typedef float f32x4  __attribute__((ext_vector_type(4)));
typedef float f32x16 __attribute__((ext_vector_type(16)));
typedef int   i32x4  __attribute__((ext_vector_type(4)));
typedef int   i32x8  __attribute__((ext_vector_type(8)));

#define AS1 __attribute__((address_space(1)))
#define AS3 __attribute__((address_space(3)))

// ---------------------------------------------------------------------------
// Kernel 1 (R32): fused quant pre-pass (R30-proven structure). Blocks
// [0, M) = per-token quant of x; blocks [M, M+WB) = weight f32->fp8.
// R32 delta: x-branch uses ONE divide (rs = 448/am) + 16 multiplies
// instead of 16 full v_div sequences (~160 VALU instr/thread -> ~20).
// Numerics: q = v*rs differs from v/(am/448) by <= 2 f32 ulp before
// fp8 RNE -> ~30 boundary flips in 16.7M elems, each ~0.008 in y
// (tolerance-passing at 0.0625).
// ---------------------------------------------------------------------------
__global__ __launch_bounds__(256) void quant_fused_kernel(
    const float* __restrict__ x, unsigned char* __restrict__ x8,
    float* __restrict__ xs, const float* __restrict__ w,
    unsigned char* __restrict__ w8, int K, int M) {
  int bid = blockIdx.x;
  int t = threadIdx.x;
  if (bid < M) {
    // ---- quant_x body ----
    int m = bid;
    const f32x4* src = (const f32x4*)(x + (size_t)m * K + t * 16);
    f32x4 v[4];
    float am = 0.0f;
#pragma unroll
    for (int i = 0; i < 4; ++i) {
      v[i] = src[i];
#pragma unroll
      for (int j = 0; j < 4; ++j) am = fmaxf(am, __builtin_fabsf(v[i][j]));
    }
#pragma unroll
    for (int off = 32; off >= 1; off >>= 1)
      am = fmaxf(am, __shfl_xor(am, off, 64));
    __shared__ float red[4];
    int wv = t >> 6, lane = t & 63;
    if (lane == 0) red[wv] = am;
    __syncthreads();
    am = fmaxf(fmaxf(red[0], red[1]), fmaxf(red[2], red[3]));
    am = fmaxf(am, 1e-12f);
    float sc = am / 448.0f;
    if (t == 0) xs[m] = sc;
    float rs = 448.0f / am;  // one divide; replaces 16
    i32x4 out;
#pragma unroll
    for (int i = 0; i < 4; ++i) {
      float q0 = v[i][0] * rs, q1 = v[i][1] * rs;
      float q2 = v[i][2] * rs, q3 = v[i][3] * rs;
      int p = __builtin_amdgcn_cvt_pk_fp8_f32(q0, q1, 0, false);
      p = __builtin_amdgcn_cvt_pk_fp8_f32(q2, q3, p, true);
      out[i] = p;
    }
    *(i32x4*)(x8 + (size_t)m * K + t * 16) = out;
  } else {
    // ---- quant_w body (R1-proven) ----
    size_t idx = (size_t)(bid - M) * 256 + t;
    const f32x4* src = (const f32x4*)w + idx * 4;
    i32x4 out;
#pragma unroll
    for (int i = 0; i < 4; ++i) {
      f32x4 v = src[i];
      int p = __builtin_amdgcn_cvt_pk_fp8_f32(v[0], v[1], 0, false);
      p = __builtin_amdgcn_cvt_pk_fp8_f32(v[2], v[3], p, true);
      out[i] = p;
    }
    ((i32x4*)w8)[idx] = out;
  }
}

// ---------------------------------------------------------------------------
// Kernel 3: MX-fp8 GEMM. R32 = R30 byte-identical (proven 157.6-158.7us).
// Structural plateau documented across R27/R28/R30 (158-160us regardless
// of schedule detail): VGPR wall (124/128 at wave 128x64; frag-dbuf needs
// +64), LDS co-residency ceiling (65536 works, 73728+ fails), shared-LDS-
// port phase-locking caps MfmaUtil at ~40% (vs 60% independent-overlap
// expectation), counted-vmcnt ledger already never drains mid-loop.
// 256 thr, 4 waves 2(wr)x2(wc), wave 128x64, block 256x128, K-64 bodies;
// LDS = A x3 (16KB @0,16384,32768) + B x2 (8KB @49152,57344) = 65536.
// Body T: read bufA(T%3), bufB(T%2); stage B(T+1)->bufB((T+1)%2), then
// A(T+2)->bufA((T+2)%3); MFMA (lgkm-optimal read order); vmcnt(4); barrier.
// Ledger: end-of-T queue = [A(T+1):4, B(T+1):2, A(T+2):4]; vmcnt(4)
// retires A(T+1)+B(T+1), leaves A(T+2) in flight ACROSS the barrier.
// WAR: stage targets = bufs last read in body T-1 (R17 rule). K-64
// layout/swizzle/anchors/staging R25/R27-validated; ratio-fold R20-
// validated; epilogue mapping R24/R25/R27-proven.
// Tripwires: LDS_Block 65536; WRITE == 131072KB; VGPR ~124; Occ ~20.
// ---------------------------------------------------------------------------
__global__ __launch_bounds__(256, 2) void gemm_mxfp8_kernel(
    const unsigned char* __restrict__ A8,   // [M][K] fp8
    const unsigned char* __restrict__ W8,   // [N][K] fp8
    const float* __restrict__ xs,           // [M]
    const float* __restrict__ wsinv,        // [N/128][K/128]
    float* __restrict__ Y,                  // [M][N] f32
    int M, int N, int K) {
  const int KB = K >> 7;  // K/128 scale tiles (32); bodies = 64

  int bid = blockIdx.x, nwg = gridDim.x;
  int wg = (bid & 7) * (nwg >> 3) + (bid >> 3);
  int mt = M >> 8;                  // 16
  int bm = wg & (mt - 1);
  int bn = wg / mt;                 // 0..63
  int m0 = bm << 8, n0 = bn << 7;   // 256 x 128 tile

  // A bufs @0,@16384,@32768 (16KB); B bufs @49152,@57344 (8KB) = 65536
  __shared__ __align__(16) char lds[65536];

  const int tid = threadIdx.x, wv = tid >> 6, lane = tid & 63;
  const int wr = wv >> 1, wc = wv & 1;          // 2 x 2 wave grid
  const int l31 = lane & 31, hi2 = lane >> 5;

  // read anchors for the K-64 interleaved layout (R25/R27-validated):
  // anchor(s) = (l31>>1)*128 + ((((l31&1)<<2)|s) ^ ((l31>>1)&7))*16
  const int lineB = (l31 >> 1) * 128;
  const int par4 = (l31 & 1) << 2;
  const int xr = (l31 >> 1) & 7;
  const int s0 = 2 * hi2, s1 = 2 * hi2 + 1;
  const int aL = wr * 8192 + lineB + ((par4 | s0) ^ xr) * 16;
  const int aH = wr * 8192 + lineB + ((par4 | s1) ^ xr) * 16;
  const int bL = wc * 4096 + lineB + ((par4 | s0) ^ xr) * 16;
  const int bH = wc * 4096 + lineB + ((par4 | s1) ^ xr) * 16;

  // staging (R25/R27-validated): dest = buf + sweep*4096 + tid*16 (linear);
  // src row = 64*sweep + 2*(tid>>3) + (inv>>2), col = (inv&3)*16.
  const int stgD = tid << 4;
  const int inv = (tid & 7) ^ ((tid >> 3) & 7);
  const int rLoc = 2 * (tid >> 3) + (inv >> 2);
  const int cSrc = (inv & 3) << 4;
  const size_t rowB = (size_t)K;  // fp8: 1 byte/elem
  const size_t g64r = 64 * rowB;  // 64-row sweep stride
  const char* pA = (const char*)A8 + (size_t)(m0 + rLoc) * rowB + cSrc;
  const char* pB = (const char*)W8 + (size_t)(n0 + rLoc) * rowB + cSrc;

  const float* wsv = wsinv + (size_t)bn * KB;  // N-tile 128 = one scale row

  f32x16 acc[4][2];
#pragma unroll
  for (int i = 0; i < 4; ++i)
#pragma unroll
    for (int j = 0; j < 2; ++j) acc[i][j] = (f32x16)0.0f;

  i32x8 af, bf[2];

#define GL(SRC, DST)                                                           \
  __builtin_amdgcn_global_load_lds((const AS1 void*)(SRC), (AS3 void*)(DST),   \
                                   16, 0, 0)
// A panel (256 rows x 64B = 16KB): 4 sweeps
#define STG_A(COND, SB, SRC)                                                   \
  if (COND) {                                                                  \
    const char* s_ = (SRC);                                                    \
    char* d_ = lds + (SB) + stgD;                                              \
    GL(s_, d_);                                                                \
    GL(s_ + g64r, d_ + 4096);                                                  \
    GL(s_ + 2 * g64r, d_ + 8192);                                              \
    GL(s_ + 3 * g64r, d_ + 12288);                                             \
  }
// B panel (128 rows x 64B = 8KB): 2 sweeps (absolute base)
#define STG_B(COND, SB, SRC)                                                   \
  if (COND) {                                                                  \
    const char* s_ = (SRC);                                                    \
    char* d_ = lds + (SB) + stgD;                                              \
    GL(s_, d_);                                                                \
    GL(s_ + g64r, d_ + 4096);                                                  \
  }

// A frag for one mj (K-64), literal buf base RB: 2 ds_read_b128 -> af
#define RD_A(RB, MJ)                                                           \
  {                                                                            \
    const char* p_ = lds + (RB) + (MJ) * 2048;                                 \
    i32x4 lo = *(const i32x4*)(p_ + aL);                                       \
    i32x4 hi = *(const i32x4*)(p_ + aH);                                       \
    af = __builtin_shufflevector(lo, hi, 0, 1, 2, 3, 4, 5, 6, 7);              \
  }
// B frag for one nj (K-64), literal buf base RB (absolute)
#define RD_B(RB, NJ)                                                           \
  {                                                                            \
    const char* p_ = lds + (RB) + (NJ) * 2048;                                 \
    i32x4 lo = *(const i32x4*)(p_ + bL);                                       \
    i32x4 hi = *(const i32x4*)(p_ + bH);                                       \
    bf[NJ] = __builtin_shufflevector(lo, hi, 0, 1, 2, 3, 4, 5, 6, 7);          \
  }

// fold + MFMA (even bodies): acc = mfma(af, bf, acc*r)
#define MMFF(MJ, NJ, R_)                                                       \
  {                                                                            \
    _Pragma("unroll") for (int q = 0; q < 16; ++q)                             \
        acc[MJ][NJ][q] *= (R_);                                                \
    acc[MJ][NJ] = __builtin_amdgcn_mfma_scale_f32_32x32x64_f8f6f4(             \
        af, bf[NJ], acc[MJ][NJ], 0, 0, 0, 0x7f7f7f7f, 0, 0x7f7f7f7f);          \
  }
// direct MFMA (odd bodies; R_ ignored): acc = mfma(af, bf, acc)
#define MMFD(MJ, NJ, R_)                                                       \
  acc[MJ][NJ] = __builtin_amdgcn_mfma_scale_f32_32x32x64_f8f6f4(               \
      af, bf[NJ], acc[MJ][NJ], 0, 0, 0, 0x7f7f7f7f, 0, 0x7f7f7f7f);

// body: lgkm-optimal order -- {B0,A0} -> MFMA(0,0) (4 reads) -> B1 ->
// MFMA(0,1) -> A1 -> MFMA(1,*) -> ... Each MFMA waits only on its own
// operands. Stages issued right after the first reads; counted vmcnt;
// 1 barrier.
#define BODY_CORE(F, R_, AR, BR, BS, AS, GB, GA, VM)                           \
  {                                                                            \
    RD_B(BR, 0);                                                               \
    RD_A(AR, 0);                                                               \
    STG_B(GB, BS, pBs);                                                        \
    STG_A(GA, AS, pAs);                                                        \
    __builtin_amdgcn_s_setprio(1);                                             \
    F(0, 0, R_);                                                               \
    __builtin_amdgcn_s_setprio(0);                                             \
    RD_B(BR, 1);                                                               \
    __builtin_amdgcn_s_setprio(1);                                             \
    F(0, 1, R_);                                                               \
    __builtin_amdgcn_s_setprio(0);                                             \
    RD_A(AR, 1);                                                               \
    __builtin_amdgcn_s_setprio(1);                                             \
    F(1, 0, R_);                                                               \
    F(1, 1, R_);                                                               \
    __builtin_amdgcn_s_setprio(0);                                             \
    RD_A(AR, 2);                                                               \
    __builtin_amdgcn_s_setprio(1);                                             \
    F(2, 0, R_);                                                               \
    F(2, 1, R_);                                                               \
    __builtin_amdgcn_s_setprio(0);                                             \
    RD_A(AR, 3);                                                               \
    __builtin_amdgcn_s_setprio(1);                                             \
    F(3, 0, R_);                                                               \
    F(3, 1, R_);                                                               \
    __builtin_amdgcn_s_setprio(0);                                             \
    asm volatile("s_waitcnt " VM ::: "memory");                                \
    __builtin_amdgcn_s_barrier();                                              \
    pAs += 64;                                                                 \
    pBs += 64;                                                                 \
  }

#define BODY_E(SC_, AR, BR, BS, AS, GB, GA, VM)                                \
  {                                                                            \
    float sc_ = (SC_);                                                         \
    float r_ = sp_ / sc_;                                                      \
    sp_ = sc_;                                                                 \
    BODY_CORE(MMFF, r_, AR, BR, BS, AS, GB, GA, VM)                            \
  }
#define BODY_O(AR, BR, BS, AS, GB, GA, VM)                                     \
  BODY_CORE(MMFD, 0.0f, AR, BR, BS, AS, GB, GA, VM)

  // prologue: A(0)->A0, B(0)->B0, A(1)->A1 (10 gloads); vmcnt(4) retires
  // A0+B0, leaves A(1):4 = steady entry invariant; barrier publishes.
  STG_A(true, 0, pA);
  STG_B(true, 49152, pB);
  STG_A(true, 16384, pA + 64);
  asm volatile("s_waitcnt vmcnt(4)" ::: "memory");
  __builtin_amdgcn_s_barrier();

  const char* pAs = pA + 128;  // A stage source (body T stages A(T+2))
  const char* pBs = pB + 64;   // B stage source (body T stages B(T+1))
  float sp_ = wsv[0];          // previous-tile scale (ratio = 1 at t = 0)

  // 6-body groups (bufA period 3 x bufB period 2), bodies 0..59;
  // body b: reads A(b%3), B(b%2); stages B->B((b+1)%2), A->A((b+2)%3).
#pragma unroll 1
  for (int t0 = 0; t0 < 30; t0 += 3) {
    float sA_ = wsv[t0], sB_ = wsv[t0 + 1], sC_ = wsv[t0 + 2];
    BODY_E(sA_, 0,     49152, 57344, 32768, true, true, "vmcnt(4)")
    BODY_O(     16384, 57344, 49152, 0,     true, true, "vmcnt(4)")
    BODY_E(sB_, 32768, 49152, 57344, 16384, true, true, "vmcnt(4)")
    BODY_O(     0,     57344, 49152, 32768, true, true, "vmcnt(4)")
    BODY_E(sC_, 16384, 49152, 57344, 0,     true, true, "vmcnt(4)")
    BODY_O(     32768, 57344, 49152, 16384, true, true, "vmcnt(4)")
  }
  // tail: bodies 60..63 (scale tiles 30, 31)
  BODY_E(wsv[30], 0,     49152, 57344, 32768, true,  true,  "vmcnt(4)")
  BODY_O(         16384, 57344, 49152, 0,     true,  true,  "vmcnt(4)")
  BODY_E(wsv[31], 32768, 49152, 57344, 0,     true,  false, "vmcnt(0)")
  BODY_O(         0,     57344, 49152, 0,     false, false, "vmcnt(0)")

#undef BODY_O
#undef BODY_E
#undef BODY_CORE
#undef MMFD
#undef MMFF
#undef RD_B
#undef RD_A
#undef STG_B
#undef STG_A
#undef GL

  // epilogue (R24/R25/R27-proven mapping, wave 128x64): col=l31,
  // row=q*8+hi2*4+j. acc is in s_last domain: Y = acc * s_last * xs[row].
  const float sl_ = sp_;
#pragma unroll
  for (int mj = 0; mj < 4; ++mj)
#pragma unroll
    for (int nj = 0; nj < 2; ++nj) {
      int col = n0 + wc * 64 + nj * 32 + l31;
#pragma unroll
      for (int q = 0; q < 4; ++q) {
        int row0 = m0 + wr * 128 + mj * 32 + q * 8 + hi2 * 4;
        f32x4 sv = *(const f32x4*)(xs + row0);
#pragma unroll
        for (int j = 0; j < 4; ++j)
          Y[(size_t)(row0 + j) * N + col] = acc[mj][nj][q * 4 + j] * sv[j] * sl_;
      }
    }
}

// ---------------------------------------------------------------------------
extern "C" void kernel_launch(void* const* d_in, const int* in_sizes, int n_in,
                              void* d_out, int out_size, void* d_ws, size_t ws_size,
                              hipStream_t stream) {
  const float* x     = (const float*)d_in[0];   // [B,S,K] f32
  const float* w     = (const float*)d_in[1];   // [N,K] f32 (fp8-representable)
  const float* wsinv = (const float*)d_in[2];   // [N/128,K/128] f32
  float* y = (float*)d_out;

  const int K = 4096;
  const int M = in_sizes[0] / K;   // 4096
  const int N = in_sizes[1] / K;   // 8192

  unsigned char* x8 = (unsigned char*)d_ws;                       // M*K
  float* xs = (float*)((char*)d_ws + (size_t)M * K);              // M floats
  unsigned char* w8 =
      (unsigned char*)d_ws + (size_t)M * K + (size_t)M * 4;       // N*K

  int wBlocks = (int)(((size_t)N * K / 16 + 255) / 256);          // 8192
  quant_fused_kernel<<<M + wBlocks, 256, 0, stream>>>(x, x8, xs, w, w8, K, M);

  dim3 grid((M / 256) * (N / 128));  // 1024
  gemm_mxfp8_kernel<<<grid, 256, 0, stream>>>(x8, w8, xs, wsinv, y, M, N, K);
}